// Round 13
// baseline (450.987 us; speedup 1.0000x reference)
//
#include <hip/hip_runtime.h>

#define B_ 8
#define S_ 32
#define N_ 512
#define E_ 8192
#define T_ 31
#define NB 512

typedef __attribute__((ext_vector_type(8))) __bf16 bf16x8;
typedef __attribute__((ext_vector_type(4))) float f32x4;
typedef unsigned short u16;
typedef unsigned int u32;

__device__ __forceinline__ u16 f2b(float f) {
    union { float f; u32 u; } v; v.f = f;
    u32 r = v.u + 0x7FFF + ((v.u >> 16) & 1);
    return (u16)(r >> 16);
}

__device__ __forceinline__ u32 cvtpk(float lo, float hi) {
    u32 r;
    asm("v_cvt_pk_bf16_f32 %0, %1, %2" : "=v"(r) : "v"(lo), "v"(hi));
    return r;
}

__device__ __forceinline__ f32x4 mfma16(bf16x8 a, bf16x8 b, f32x4 c) {
    return __builtin_amdgcn_mfma_f32_16x16x32_bf16(a, b, c, 0, 0, 0);
}

// device-scope grid barrier (all NB blocks resident by construction)
__device__ __forceinline__ void gridbar(int* cnt, int* gen) {
    __syncthreads();
    if (threadIdx.x == 0) {
        __threadfence();
        int my = __hip_atomic_load(gen, __ATOMIC_ACQUIRE, __HIP_MEMORY_SCOPE_AGENT);
        int v = __hip_atomic_fetch_add(cnt, 1, __ATOMIC_ACQ_REL, __HIP_MEMORY_SCOPE_AGENT);
        if (v == NB - 1) {
            __hip_atomic_store(cnt, 0, __ATOMIC_RELAXED, __HIP_MEMORY_SCOPE_AGENT);
            __hip_atomic_fetch_add(gen, 1, __ATOMIC_RELEASE, __HIP_MEMORY_SCOPE_AGENT);
        } else {
            while (__hip_atomic_load(gen, __ATOMIC_ACQUIRE, __HIP_MEMORY_SCOPE_AGENT) == my)
                __builtin_amdgcn_s_sleep(2);
        }
        __threadfence();
    }
    __syncthreads();
}

__global__ void bar_init_k(int* bar) {
    if (threadIdx.x < 2) bar[threadIdx.x] = 0;
}

// ---------------- one persistent kernel: setup -> deg -> dis -> scat -> y -> fused ----------------
__launch_bounds__(256, 2)
__global__ void mega_k(const float* __restrict__ x, const int* __restrict__ ei,
                       const float* __restrict__ ew,
                       const float* __restrict__ start_w, const float* __restrict__ start_b,
                       const float* __restrict__ filt_w, const float* __restrict__ filt_b,
                       const float* __restrict__ gate_w, const float* __restrict__ gate_b,
                       const float* __restrict__ gcn_w, const float* __restrict__ gcn_b,
                       const float* __restrict__ skip_w, const float* __restrict__ skip_b,
                       const float* __restrict__ end1_w, const float* __restrict__ end1_b,
                       const float* __restrict__ end2_w, const float* __restrict__ end2_b,
                       float* __restrict__ S, float* __restrict__ rs, float* __restrict__ dis,
                       float* __restrict__ deg, float* __restrict__ coef,
                       u16* __restrict__ W1, u16* __restrict__ W2, u16* __restrict__ W3,
                       float* __restrict__ Y, int* __restrict__ bar,
                       float* __restrict__ out) {
    __shared__ __align__(16) char smem[47104];
    const int tid = threadIdx.x;
    const int bid = blockIdx.x;
    const int gtid = bid * 256 + tid;
    int* cnt = bar;
    int* gen = bar + 1;

    // ================= P0: zero + out-init + weight tiling + coef =================
    if (bid == 511) {
        // coef collapse (uses <=40KB of smem, staged in halves)
        float* W  = (float*)smem;                    // 8192 f32
        float* sw = (float*)(smem + 32768);
        float* sb = (float*)(smem + 33024);
        float* A0 = (float*)(smem + 33280);
        float* A1 = (float*)(smem + 33536);
        float* C0 = (float*)(smem + 33792);
        float (*r0)[4] = (float(*)[4])(smem + 34048);
        float (*r1)[4] = (float(*)[4])(smem + 35072);
        float (*r2)[4] = (float(*)[4])(smem + 36096);
        if (tid < 64) { sw[tid] = start_w[tid]; sb[tid] = start_b[tid]; }
#pragma unroll
        for (int k = 0; k < 32; ++k) W[tid + k * 256] = filt_w[tid + k * 256];
        __syncthreads();
        {   int o = tid & 63, q = tid >> 6;
            float a0 = 0, a1 = 0, c = 0;
            for (int rr = 0; rr < 16; ++rr) {
                int r = q * 16 + ((rr + o) & 15);
                float f0 = W[(o * 64 + r) * 2], f1 = W[(o * 64 + r) * 2 + 1];
                a0 += f0 * sw[r]; a1 += f1 * sw[r]; c += (f0 + f1) * sb[r];
            }
            r0[o][q] = a0; r1[o][q] = a1; r2[o][q] = c;
        }
        __syncthreads();
        if (tid < 64) {
            A0[tid] = r0[tid][0] + r0[tid][1] + r0[tid][2] + r0[tid][3];
            A1[tid] = r1[tid][0] + r1[tid][1] + r1[tid][2] + r1[tid][3];
            C0[tid] = r2[tid][0] + r2[tid][1] + r2[tid][2] + r2[tid][3] + filt_b[tid];
        }
        __syncthreads();
#pragma unroll
        for (int k = 0; k < 32; ++k) W[tid + k * 256] = gate_w[tid + k * 256];
        __syncthreads();
        {   int o = tid & 63, q = tid >> 6;
            float a0 = 0, a1 = 0, c = 0;
            for (int rr = 0; rr < 16; ++rr) {
                int r = q * 16 + ((rr + o) & 15);
                float f0 = W[(o * 64 + r) * 2], f1 = W[(o * 64 + r) * 2 + 1];
                a0 += f0 * sw[r]; a1 += f1 * sw[r]; c += (f0 + f1) * sb[r];
            }
            r0[o][q] = a0; r1[o][q] = a1; r2[o][q] = c;
        }
        __syncthreads();
        if (tid < 64) {
            coef[192 + tid] = r0[tid][0] + r0[tid][1] + r0[tid][2] + r0[tid][3];
            coef[256 + tid] = r1[tid][0] + r1[tid][1] + r1[tid][2] + r1[tid][3];
            coef[320 + tid] = r2[tid][0] + r2[tid][1] + r2[tid][2] + r2[tid][3] + gate_b[tid];
        }
        __syncthreads();
#pragma unroll
        for (int k = 0; k < 16; ++k) W[tid + k * 256] = gcn_w[tid + k * 256];
        __syncthreads();
        {   int o = tid & 63, q = tid >> 6;
            float u0 = 0, u1 = 0, u2 = 0;
            for (int dd = 0; dd < 16; ++dd) {
                int d = q * 16 + ((dd + o) & 15);
                float g = W[o * 64 + d];
                u0 += g * A0[d]; u1 += g * A1[d]; u2 += g * C0[d];
            }
            r0[o][q] = u0; r1[o][q] = u1; r2[o][q] = u2;
        }
        __syncthreads();
        if (tid < 64) {
            coef[tid]       = r0[tid][0] + r0[tid][1] + r0[tid][2] + r0[tid][3];
            coef[64 + tid]  = r1[tid][0] + r1[tid][1] + r1[tid][2] + r1[tid][3];
            coef[128 + tid] = r2[tid][0] + r2[tid][1] + r2[tid][2] + r2[tid][3];
        }
    } else {
        // blocks 0..510: zero + out-init + weight tiling (stride 130816)
        for (int i = gtid; i < 262144; i += 130816) S[i] = 0.f;
        if (gtid < 512) { deg[gtid] = 0.f; rs[gtid] = 0.f; }
        for (int i = gtid; i < 49152; i += 130816) out[i] = end2_b[(i >> 9) % 12];
        for (int i = gtid; i < 131072; i += 130816) {   // W2T
            int m = i & 7, lane = (i >> 3) & 63, ii = (i >> 9) & 3;
            int kkI = (i >> 11) & 7, pw = (i >> 14) & 1, wid = (i >> 15) & 3;
            int er = wid * 128 + pw * 64 + ii * 16 + (lane & 15);
            int col = kkI * 32 + (lane >> 4) * 8 + m;
            W2[i] = f2b(end1_w[er * 256 + col]);
        }
        if (gtid < 16384) {   // W1T
            int i = gtid;
            int m = i & 7, lane = (i >> 3) & 63, ii = (i >> 9) & 3;
            int kkI = (i >> 11) & 1, wid = (i >> 12) & 3;
            int sr = wid * 64 + ii * 16 + (lane & 15);
            int col = kkI * 32 + (lane >> 4) * 8 + m;
            W1[i] = f2b(skip_w[sr * 64 + col]);
        }
        if (gtid < 8192) {    // W3T (k'-permutation matching GEMM2 C-fragment)
            int i = gtid;
            int m = i & 7, lane = (i >> 3) & 63, c = (i >> 9) & 1;
            int pw = (i >> 10) & 1, wid = (i >> 11) & 3;
            int p = lane & 15;
            int k = wid * 128 + pw * 64 + c * 32 + (lane >> 4) * 8 + m;
            int e = (k & 0x1E0) | (((k >> 3) & 3) << 2) | (k & 3) | (((k >> 2) & 1) << 4);
            W3[i] = f2b((p < 12) ? end2_w[p * 512 + e] : 0.f);
        }
    }
    gridbar(cnt, gen);

    // ================= P1: degree atomics =================
    if (gtid < E_) atomicAdd(deg + ei[E_ + gtid], ew[gtid]);
    gridbar(cnt, gen);

    // ================= P2: dis (self-loop +1 folded) =================
    if (gtid < 512) dis[gtid] = rsqrtf(deg[gtid] + 1.f);
    gridbar(cnt, gen);

    // ================= P3: scatter S + rowsum =================
    if (gtid < E_ + N_) {
        int row, col; float w;
        if (gtid < E_) { row = ei[gtid]; col = ei[E_ + gtid]; w = ew[gtid]; }
        else           { row = col = gtid - E_;               w = 1.f;  }
        float nv = dis[row] * w * dis[col];
        atomicAdd(S + row * N_ + col, nv);
        atomicAdd(rs + col, nv);
    }
    gridbar(cnt, gen);

    // ================= P4: Y quarters (512 blocks, 1:1) =================
    {
        float (*xs)[128] = (float(*)[128])smem;
        const int m = (bid & 1) * 256 + tid;
        const int q = (bid >> 1) & 3;
        const int ns = q * 128;
        const int bt0 = (bid >> 3) * 4;
#pragma unroll
        for (int i = 0; i < 2; ++i) {
            int idx = tid + i * 256;
            xs[idx >> 7][idx & 127] = x[(bt0 + (idx >> 7)) * 512 + ns + (idx & 127)];
        }
        __syncthreads();
        float a0 = 0, a1 = 0, a2 = 0, a3 = 0;
#pragma unroll 8
        for (int n = 0; n < 128; ++n) {
            float sv = S[(ns + n) * 512 + m];
            a0 += xs[0][n] * sv; a1 += xs[1][n] * sv;
            a2 += xs[2][n] * sv; a3 += xs[3][n] * sv;
        }
        float* Yd = Y + q * 131072;
        Yd[(bt0 + 0) * 512 + m] = a0; Yd[(bt0 + 1) * 512 + m] = a1;
        Yd[(bt0 + 2) * 512 + m] = a2; Yd[(bt0 + 3) * 512 + m] = a3;
    }
    gridbar(cnt, gen);

    // ================= P5: fused tiles (grid-stride, body = round 12) =================
    u16* HG = (u16*)smem;                          // 8 KB
    u16* SK = (u16*)(smem + 8192);                 // 32 KB (reused f32)
    float* xs0 = (float*)(smem + 40960);
    float* xs1 = (float*)(smem + 41216);
    float* ys0 = (float*)(smem + 41472);
    float* ys1 = (float*)(smem + 41728);
    float* rsl = (float*)(smem + 41984);
    float* cf  = (float*)(smem + 42240);           // 384 f32
    float* gb  = (float*)(smem + 43776);
    float* bsk = (float*)(smem + 44032);
    float* be1 = (float*)(smem + 45056);

    const int wid = tid >> 6;
    const int lane = tid & 63;
    const int lr = lane & 15;
    const int lh = lane >> 4;

    // block-constant staging (once)
    cf[tid] = coef[tid];
    if (tid < 128) cf[256 + tid] = coef[256 + tid];
    if (tid >= 128 && tid < 192) gb[tid - 128] = gcn_b[tid - 128];
    bsk[tid] = skip_b[tid];
    be1[tid] = end1_b[tid];
    be1[tid + 256] = end1_b[tid + 256];

    // W1 fragment preload (once)
    bf16x8 a1f[2][4];
    {
        const u16* w1b = W1 + wid * 4096 + lane * 8;
#pragma unroll
        for (int kkI = 0; kkI < 2; ++kkI)
#pragma unroll
            for (int i = 0; i < 4; ++i)
                a1f[kkI][i] = *(const bf16x8*)(w1b + kkI * 2048 + i * 512);
    }

    for (int tile = bid; tile < 1984; tile += NB) {
        const int ntile = tile & 7;
        const int btix = tile >> 3;
        const int t = btix % 31;
        const int b = btix / 31;
        const int n0 = ntile * 64;
        const int bt = b * 32 + t;

        if (tid < 64) {
            const int a0 = bt * 512 + n0 + tid, a1 = (bt + 1) * 512 + n0 + tid;
            xs0[tid] = x[a0];
            xs1[tid] = x[a1];
            ys0[tid] = Y[a0] + Y[131072 + a0] + Y[262144 + a0] + Y[393216 + a0];
            ys1[tid] = Y[a1] + Y[131072 + a1] + Y[262144 + a1] + Y[393216 + a1];
            rsl[tid] = rs[n0 + tid];
        }
        __syncthreads();

        // phase A
#pragma unroll
        for (int k = 0; k < 8; ++k) {
            const int v = tid + k * 256;
            const int pix = v >> 5;
            const int o0 = (v & 31) << 1;
            float hv[2];
#pragma unroll
            for (int q = 0; q < 2; ++q) {
                const int o = o0 + q;
                const float fgv = cf[o] * ys0[pix] + cf[64 + o] * ys1[pix]
                                + cf[128 + o] * rsl[pix] + gb[o];
                const float ggv = cf[192 + o] * xs0[pix] + cf[256 + o] * xs1[pix] + cf[320 + o];
                const float e2f = __expf(2.f * fgv);
                const float eg  = __expf(ggv);
                hv[q] = __fdividef((e2f - 1.f) * eg, (e2f + 1.f) * (1.f + eg));
            }
            *(u32*)(HG + (pix << 6) + (o0 ^ ((pix & 7) << 3))) = cvtpk(hv[0], hv[1]);
        }
        __syncthreads();

        // GEMM1
        {
            f32x4 acc[4][4];
#pragma unroll
            for (int i = 0; i < 4; ++i) {
                const f32x4 binit = *(const f32x4*)&bsk[wid * 64 + i * 16 + lh * 4];
#pragma unroll
                for (int j = 0; j < 4; ++j) acc[i][j] = binit;
            }
#pragma unroll
            for (int kkI = 0; kkI < 2; ++kkI) {
                const int kb = kkI * 32 + lh * 8;
                bf16x8 bv[4];
#pragma unroll
                for (int j = 0; j < 4; ++j) {
                    const int pr = j * 16 + lr;
                    bv[j] = *(const bf16x8*)(HG + (pr << 6) + (kb ^ ((pr & 7) << 3)));
                }
#pragma unroll
                for (int i = 0; i < 4; ++i)
#pragma unroll
                    for (int j = 0; j < 4; ++j)
                        acc[i][j] = mfma16(a1f[kkI][i], bv[j], acc[i][j]);
            }
#pragma unroll
            for (int i = 0; i < 4; ++i) {
#pragma unroll
                for (int j = 0; j < 4; ++j) {
                    const int pix = j * 16 + lr;
                    const int xw = (pix & 7) << 3;
                    const int s = wid * 64 + i * 16 + lh * 4;
                    const u32 w0 = cvtpk(fmaxf(acc[i][j][0], 0.f), fmaxf(acc[i][j][1], 0.f));
                    const u32 w1 = cvtpk(fmaxf(acc[i][j][2], 0.f), fmaxf(acc[i][j][3], 0.f));
                    *(u32*)(SK + (pix << 8) + (s ^ xw)) = w0;
                    *(u32*)(SK + (pix << 8) + ((s + 2) ^ xw)) = w1;
                }
            }
        }
        __syncthreads();

        // GEMM2 + GEMM3
        {
            f32x4 acc_out[4];
#pragma unroll
            for (int j = 0; j < 4; ++j) acc_out[j] = (f32x4){0.f, 0.f, 0.f, 0.f};

#pragma unroll
            for (int pass = 0; pass < 2; ++pass) {
                const int ep = wid * 128 + pass * 64;
                const u16* w2b = W2 + (wid * 2 + pass) * 16384 + lane * 8;
                bf16x8 bfr[2];
#pragma unroll
                for (int c = 0; c < 2; ++c)
                    bfr[c] = *(const bf16x8*)(W3 + (wid * 2 + pass) * 1024 + c * 512 + lane * 8);
                f32x4 acc[4][4];
#pragma unroll
                for (int i = 0; i < 4; ++i) {
                    const f32x4 binit = *(const f32x4*)&be1[ep + i * 16 + lh * 4];
#pragma unroll
                    for (int j = 0; j < 4; ++j) acc[i][j] = binit;
                }
                bf16x8 aC[4], aN[4];
#pragma unroll
                for (int i = 0; i < 4; ++i) aC[i] = *(const bf16x8*)(w2b + i * 512);
#pragma unroll
                for (int i = 0; i < 4; ++i) aN[i] = *(const bf16x8*)(w2b + 2048 + i * 512);
#pragma unroll
                for (int kkI = 0; kkI < 8; ++kkI) {
                    bf16x8 aN2[4];
                    if (kkI < 6) {
#pragma unroll
                        for (int i = 0; i < 4; ++i)
                            aN2[i] = *(const bf16x8*)(w2b + (kkI + 2) * 2048 + i * 512);
                    }
                    const int kb = kkI * 32 + lh * 8;
                    bf16x8 bv[4];
#pragma unroll
                    for (int j = 0; j < 4; ++j) {
                        const int pr = j * 16 + lr;
                        bv[j] = *(const bf16x8*)(SK + (pr << 8) + (kb ^ ((pr & 7) << 3)));
                    }
#pragma unroll
                    for (int i = 0; i < 4; ++i)
#pragma unroll
                        for (int j = 0; j < 4; ++j)
                            acc[i][j] = mfma16(aC[i], bv[j], acc[i][j]);
                    if (kkI < 7) {
#pragma unroll
                        for (int i = 0; i < 4; ++i) aC[i] = aN[i];
                        if (kkI < 6) {
#pragma unroll
                            for (int i = 0; i < 4; ++i) aN[i] = aN2[i];
                        }
                    }
                }
                u32 pk[4][4][2];
#pragma unroll
                for (int i = 0; i < 4; ++i) {
#pragma unroll
                    for (int j = 0; j < 4; ++j) {
                        pk[i][j][0] = cvtpk(fmaxf(acc[i][j][0], 0.f), fmaxf(acc[i][j][1], 0.f));
                        pk[i][j][1] = cvtpk(fmaxf(acc[i][j][2], 0.f), fmaxf(acc[i][j][3], 0.f));
                    }
                }
#pragma unroll
                for (int j = 0; j < 4; ++j) {
#pragma unroll
                    for (int c = 0; c < 2; ++c) {
                        union { u32 w[4]; bf16x8 v; } af;
                        af.w[0] = pk[2 * c][j][0];
                        af.w[1] = pk[2 * c][j][1];
                        af.w[2] = pk[2 * c + 1][j][0];
                        af.w[3] = pk[2 * c + 1][j][1];
                        acc_out[j] = mfma16(af.v, bfr[c], acc_out[j]);
                    }
                }
            }
            __syncthreads();   // all waves done reading SK; reuse as f32 scratch

            float* SKf = (float*)SK;
#pragma unroll
            for (int j = 0; j < 4; ++j)
#pragma unroll
                for (int r = 0; r < 4; ++r)
                    SKf[wid * 1024 + (j * 16 + lh * 4 + r) * 16 + lr] = acc_out[j][r];
        }
        __syncthreads();

        // cross-wave reduce + atomic accumulate into out
        {
            const f32x4* Sv = (const f32x4*)SK;
            f32x4 sum = Sv[tid] + Sv[256 + tid] + Sv[512 + tid] + Sv[768 + tid];
            const int pix = tid >> 2;
            const int p0 = (tid & 3) << 2;
            if (p0 < 12) {
#pragma unroll
                for (int r = 0; r < 4; ++r)
                    atomicAdd(out + (b * 12 + p0 + r) * 512 + n0 + pix, sum[r] * (1.f / 31.f));
            }
        }
        __syncthreads();   // protect smem reuse before next tile's staging
    }
}

extern "C" void kernel_launch(void* const* d_in, const int* in_sizes, int n_in,
                              void* d_out, int out_size, void* d_ws, size_t ws_size,
                              hipStream_t stream) {
    const float* x       = (const float*)d_in[0];
    const int*   ei      = (const int*)  d_in[1];
    const float* ew      = (const float*)d_in[2];
    const float* start_w = (const float*)d_in[3];
    const float* start_b = (const float*)d_in[4];
    const float* filt_w  = (const float*)d_in[5];
    const float* filt_b  = (const float*)d_in[6];
    const float* gate_w  = (const float*)d_in[7];
    const float* gate_b  = (const float*)d_in[8];
    const float* gcn_w   = (const float*)d_in[9];
    const float* gcn_b   = (const float*)d_in[10];
    const float* skip_w  = (const float*)d_in[13];
    const float* skip_b  = (const float*)d_in[14];
    const float* end1_w  = (const float*)d_in[15];
    const float* end1_b  = (const float*)d_in[16];
    const float* end2_w  = (const float*)d_in[17];
    const float* end2_b  = (const float*)d_in[18];
    float* out = (float*)d_out;

    char* ws = (char*)d_ws;
    float* S    = (float*)(ws);                 // 1,048,576 B
    float* rs   = (float*)(ws + 1050624);       // 2048 B
    float* dis  = (float*)(ws + 1052672);       // 2048 B
    float* deg  = (float*)(ws + 1054720);       // 2048 B
    float* coef = (float*)(ws + 1579008);       // 1536 B
    u16*   W1   = (u16*)  (ws + 1580544);       // 32,768 B
    u16*   W2   = (u16*)  (ws + 1613312);       // 262,144 B
    u16*   W3   = (u16*)  (ws + 1875456);       // 16,384 B
    float* Y    = (float*)(ws + 1891840);       // 4 x 524,288 B quarter-partials
    int*   bar  = (int*)  (ws + 3989504);       // 2 ints (cnt, gen)

    hipLaunchKernelGGL(bar_init_k, dim3(1), dim3(64), 0, stream, bar);
    hipLaunchKernelGGL(mega_k, dim3(NB), dim3(256), 0, stream,
                       x, ei, ew, start_w, start_b, filt_w, filt_b, gate_w, gate_b,
                       gcn_w, gcn_b, skip_w, skip_b, end1_w, end1_b, end2_w, end2_b,
                       S, rs, dis, deg, coef, W1, W2, W3, Y, bar, out);
}

// Round 14
// 82.653 us; speedup vs baseline: 5.4564x; 5.4564x over previous
//
#include <hip/hip_runtime.h>

#define B_ 8
#define S_ 32
#define N_ 512
#define E_ 8192
#define T_ 31

typedef __attribute__((ext_vector_type(8))) __bf16 bf16x8;
typedef __attribute__((ext_vector_type(4))) float f32x4;
typedef unsigned short u16;
typedef unsigned int u32;

__device__ __forceinline__ u16 f2b(float f) {
    union { float f; u32 u; } v; v.f = f;
    u32 r = v.u + 0x7FFF + ((v.u >> 16) & 1);
    return (u16)(r >> 16);
}

// packed f32x2 -> bf16x2 (RNE), single VALU op
__device__ __forceinline__ u32 cvtpk(float lo, float hi) {
    u32 r;
    asm("v_cvt_pk_bf16_f32 %0, %1, %2" : "=v"(r) : "v"(lo), "v"(hi));
    return r;
}

__device__ __forceinline__ f32x4 mfma16(bf16x8 a, bf16x8 b, f32x4 c) {
    return __builtin_amdgcn_mfma_f32_16x16x32_bf16(a, b, c, 0, 0, 0);
}

// ---------------- adjacency: degree ----------------
__global__ void deg_k(const int* __restrict__ ei, const float* __restrict__ ew,
                      float* __restrict__ deg) {
    int e = blockIdx.x * 256 + threadIdx.x;
    if (e >= E_ + N_) return;
    int col; float w;
    if (e < E_) { col = ei[E_ + e]; w = ew[e]; }
    else        { col = e - E_;     w = 1.f;  }
    atomicAdd(deg + col, w);
}

// ---------------- dis + coefficient collapse + out-init (merged) ----------------
__global__ void dis_coef_k(const float* __restrict__ deg, float* __restrict__ dis,
                           const float* __restrict__ start_w, const float* __restrict__ start_b,
                           const float* __restrict__ filt_w, const float* __restrict__ filt_b,
                           const float* __restrict__ gate_w, const float* __restrict__ gate_b,
                           const float* __restrict__ gcn_w, float* __restrict__ coef,
                           const float* __restrict__ end2_b, float* __restrict__ out) {
    if (blockIdx.x >= 3) {           // out[i] = end2_b[p] (bias pre-init for atomics)
        int i = (blockIdx.x - 3) * 256 + threadIdx.x;   // < 8*12*512
        out[i] = end2_b[(i >> 9) % 12];
        return;
    }
    if (blockIdx.x < 2) {
        int n = blockIdx.x * 256 + threadIdx.x;
        float d = deg[n];
        dis[n] = (d > 0.f) ? rsqrtf(d) : 0.f;
        return;
    }
    // coef block: 256 threads, parallel reductions
    __shared__ float W[16384];               // filt (8K) + gate (8K) staged coalesced
    __shared__ float sw[64], sb[64], A0[64], A1[64], C0[64];
    __shared__ float r0[128][2], r1[128][2], r2[128][2];
    __shared__ float u0s[64][4], u1s[64][4], u2s[64][4];
    const int tid = threadIdx.x;
    if (tid < 64) { sw[tid] = start_w[tid]; sb[tid] = start_b[tid]; }
#pragma unroll
    for (int k = 0; k < 32; ++k) W[tid + k * 256] = filt_w[tid + k * 256];
#pragma unroll
    for (int k = 0; k < 32; ++k) W[8192 + tid + k * 256] = gate_w[tid + k * 256];
    __syncthreads();
    {   // stage 1: 128 tasks (64 filt + 64 gate), r-loop split 2-way
        const int task = tid >> 1, half = tid & 1;
        const int o = task & 63;
        const float* Wb = W + ((task >= 64) ? 8192 : 0);
        float a0 = 0, a1 = 0, c = 0;
        for (int rr = 0; rr < 32; ++rr) {
            int r = (half * 32 + rr + o) & 63;     // skew spreads banks
            float f0 = Wb[(o * 64 + r) * 2], f1 = Wb[(o * 64 + r) * 2 + 1];
            a0 += f0 * sw[r]; a1 += f1 * sw[r]; c += (f0 + f1) * sb[r];
        }
        r0[task][half] = a0; r1[task][half] = a1; r2[task][half] = c;
    }
    __syncthreads();
    if (tid < 128) {
        const int o = tid & 63;
        float a0 = r0[tid][0] + r0[tid][1];
        float a1 = r1[tid][0] + r1[tid][1];
        float c  = r2[tid][0] + r2[tid][1];
        if (tid < 64) { A0[o] = a0; A1[o] = a1; C0[o] = c + filt_b[o]; }
        else { coef[192 + o] = a0; coef[256 + o] = a1; coef[320 + o] = c + gate_b[o]; }
    }
    __syncthreads();
#pragma unroll
    for (int k = 0; k < 16; ++k) W[tid + k * 256] = gcn_w[tid + k * 256];
    __syncthreads();
    {   // stage 2: 64 outputs, d-loop split 4-way
        const int o = tid & 63, q = tid >> 6;
        float u0 = 0, u1 = 0, u2 = 0;
        for (int dd = 0; dd < 16; ++dd) {
            int d = q * 16 + ((dd + o) & 15);
            float g = W[o * 64 + d];
            u0 += g * A0[d]; u1 += g * A1[d]; u2 += g * C0[d];
        }
        u0s[o][q] = u0; u1s[o][q] = u1; u2s[o][q] = u2;
    }
    __syncthreads();
    if (tid < 64) {
        const int o = tid;
        coef[o]       = u0s[o][0] + u0s[o][1] + u0s[o][2] + u0s[o][3];
        coef[64 + o]  = u1s[o][0] + u1s[o][1] + u1s[o][2] + u1s[o][3];
        coef[128 + o] = u2s[o][0] + u2s[o][1] + u2s[o][2] + u2s[o][3];
    }
}

// ---------------- scatter (S + rowsum) + weight tiling (merged) ----------------
// W1T/W2T/W3T in exact per-MFMA-load fragment order (1KB contiguous wave reads).
__global__ void scat_wconv_k(const int* __restrict__ ei, const float* __restrict__ ew,
                             const float* __restrict__ dis,
                             const float* __restrict__ skip_w, const float* __restrict__ end1_w,
                             const float* __restrict__ end2_w,
                             u16* __restrict__ W1, u16* __restrict__ W2, u16* __restrict__ W3,
                             float* __restrict__ S, float* __restrict__ rs) {
    const int bid = blockIdx.x;
    if (bid < 512) {
        int i = bid * 256 + threadIdx.x;     // < 131072
        {   // W2T
            int m = i & 7, lane = (i >> 3) & 63, ii = (i >> 9) & 3;
            int kkI = (i >> 11) & 7, pw = (i >> 14) & 1, wid = (i >> 15) & 3;
            int er = wid * 128 + pw * 64 + ii * 16 + (lane & 15);
            int col = kkI * 32 + (lane >> 4) * 8 + m;
            W2[i] = f2b(end1_w[er * 256 + col]);
        }
        if (i < 16384) {   // W1T
            int m = i & 7, lane = (i >> 3) & 63, ii = (i >> 9) & 3;
            int kkI = (i >> 11) & 1, wid = (i >> 12) & 3;
            int sr = wid * 64 + ii * 16 + (lane & 15);
            int col = kkI * 32 + (lane >> 4) * 8 + m;
            W1[i] = f2b(skip_w[sr * 64 + col]);
        }
        if (i < 8192) {    // W3T (with k'-permutation matching GEMM2 C-fragment)
            int m = i & 7, lane = (i >> 3) & 63, c = (i >> 9) & 1;
            int pw = (i >> 10) & 1, wid = (i >> 11) & 3;
            int p = lane & 15;
            int k = wid * 128 + pw * 64 + c * 32 + (lane >> 4) * 8 + m;
            int e = (k & 0x1E0) | (((k >> 3) & 3) << 2) | (k & 3) | (((k >> 2) & 1) << 4);
            W3[i] = f2b((p < 12) ? end2_w[p * 512 + e] : 0.f);
        }
        return;
    }
    int e = (bid - 512) * 256 + threadIdx.x;
    if (e >= E_ + N_) return;
    int row, col; float w;
    if (e < E_) { row = ei[e]; col = ei[E_ + e]; w = ew[e]; }
    else        { row = col = e - E_;            w = 1.f;  }
    float nv = dis[row] * w * dis[col];
    atomicAdd(S + row * N_ + col, nv);        // S[src*N+tgt] = A_hat[tgt,src]
    atomicAdd(rs + col, nv);                  // rs[tgt] = row-sum of A_hat
}

// ---------------- Y: n-split quarters. Yq[bt,m] = sum_{n in q} S[n,m]*x[bt,n] ----------------
__global__ void y_k(const float* __restrict__ x, const float* __restrict__ S,
                    float* __restrict__ Y) {
    __shared__ float xs[4][128];
    const int tid = threadIdx.x;
    const int m = (blockIdx.x & 1) * 256 + tid;
    const int q = blockIdx.x >> 1;           // 0..3
    const int ns = q * 128;
    const int bt0 = blockIdx.y * 4;
#pragma unroll
    for (int i = 0; i < 2; ++i) {
        int idx = tid + i * 256;             // < 512
        xs[idx >> 7][idx & 127] = x[(bt0 + (idx >> 7)) * 512 + ns + (idx & 127)];
    }
    __syncthreads();
    float a0 = 0, a1 = 0, a2 = 0, a3 = 0;
#pragma unroll 8
    for (int n = 0; n < 128; ++n) {
        float sv = S[(ns + n) * 512 + m];
        a0 += xs[0][n] * sv; a1 += xs[1][n] * sv;
        a2 += xs[2][n] * sv; a3 += xs[3][n] * sv;
    }
    float* Yd = Y + q * 131072;              // quarter-partial buffer
    Yd[(bt0 + 0) * 512 + m] = a0; Yd[(bt0 + 1) * 512 + m] = a1;
    Yd[(bt0 + 2) * 512 + m] = a2; Yd[(bt0 + 3) * 512 + m] = a3;
}

// ---------------- fused hg -> skip -> end1 -> end2 ----------------
// (256,2), 4 waves, 64 pixels — the verified no-spill point. W1 slice preloaded
// at entry (in flight during phase A); W2 depth-1 software pipeline; W3 hoisted.
__launch_bounds__(256, 2)
__global__ void fused_k(const float* __restrict__ x, const float* __restrict__ Y,
                        const float* __restrict__ rs, const float* __restrict__ coef,
                        const float* __restrict__ gcn_b, const float* __restrict__ skip_b,
                        const float* __restrict__ end1_b,
                        const u16* __restrict__ W1, const u16* __restrict__ W2,
                        const u16* __restrict__ W3, float* __restrict__ out) {
    __shared__ __align__(16) u16 HG[64 * 64];    // [pix][o]   swizzled  (8 KB)
    __shared__ __align__(16) u16 SK[64 * 256];   // [pix][s]   swizzled  (32 KB; reused f32)
    __shared__ float xs0[64], xs1[64], ys0[64], ys1[64], rsl[64];
    __shared__ float cf[384], gb[64];
    __shared__ __align__(16) float bsk[256], be1[512];

    const int tid = threadIdx.x;
    const int wid = tid >> 6;
    const int lane = tid & 63;
    const int lr = lane & 15;
    const int lh = lane >> 4;

    const int bid = blockIdx.x;
    const int ntile = bid & 7;
    const int btix = bid >> 3;       // b*31 + t
    const int t = btix % 31;
    const int b = btix / 31;
    const int n0 = ntile * 64;
    const int bt = b * 32 + t;

    // preload full W1 slice (8 frags, 32 VGPRs) — in flight through phase A
    bf16x8 a1f[2][4];
    {
        const u16* w1b = W1 + wid * 4096 + lane * 8;
#pragma unroll
        for (int kkI = 0; kkI < 2; ++kkI)
#pragma unroll
            for (int i = 0; i < 4; ++i)
                a1f[kkI][i] = *(const bf16x8*)(w1b + kkI * 2048 + i * 512);
    }

    if (tid < 64) {
        const int a0 = bt * 512 + n0 + tid, a1 = (bt + 1) * 512 + n0 + tid;
        xs0[tid] = x[a0];
        xs1[tid] = x[a1];
        ys0[tid] = Y[a0] + Y[131072 + a0] + Y[262144 + a0] + Y[393216 + a0];
        ys1[tid] = Y[a1] + Y[131072 + a1] + Y[262144 + a1] + Y[393216 + a1];
        rsl[tid] = rs[n0 + tid];
        gb[tid]  = gcn_b[tid];
    }
    cf[tid] = coef[tid];
    if (tid < 128) cf[256 + tid] = coef[256 + tid];
    bsk[tid] = skip_b[tid];
    be1[tid] = end1_b[tid];
    be1[tid + 256] = end1_b[tid + 256];
    __syncthreads();

    // phase A: hg = tanh(fg) * sigmoid(g), 2 o-values/thread, packed u32 write
#pragma unroll
    for (int k = 0; k < 8; ++k) {
        const int v = tid + k * 256;         // < 2048
        const int pix = v >> 5;
        const int o0 = (v & 31) << 1;
        float hv[2];
#pragma unroll
        for (int q = 0; q < 2; ++q) {
            const int o = o0 + q;
            const float fgv = cf[o] * ys0[pix] + cf[64 + o] * ys1[pix]
                            + cf[128 + o] * rsl[pix] + gb[o];
            const float ggv = cf[192 + o] * xs0[pix] + cf[256 + o] * xs1[pix] + cf[320 + o];
            const float e2f = __expf(2.f * fgv);
            const float eg  = __expf(ggv);
            hv[q] = __fdividef((e2f - 1.f) * eg, (e2f + 1.f) * (1.f + eg));
        }
        *(u32*)(HG + (pix << 6) + (o0 ^ ((pix & 7) << 3))) = cvtpk(hv[0], hv[1]);
    }
    __syncthreads();

    // GEMM1 (transposed): SKIP^T = skip_w x HG^T.  A=a1f (preloaded), B=HG (LDS)
    {
        f32x4 acc[4][4];
#pragma unroll
        for (int i = 0; i < 4; ++i)
#pragma unroll
            for (int j = 0; j < 4; ++j) acc[i][j] = (f32x4){0.f, 0.f, 0.f, 0.f};
#pragma unroll
        for (int kkI = 0; kkI < 2; ++kkI) {
            const int kb = kkI * 32 + lh * 8;
            bf16x8 bv[4];
#pragma unroll
            for (int j = 0; j < 4; ++j) {
                const int pr = j * 16 + lr;
                bv[j] = *(const bf16x8*)(HG + (pr << 6) + (kb ^ ((pr & 7) << 3)));
            }
#pragma unroll
            for (int i = 0; i < 4; ++i)
#pragma unroll
                for (int j = 0; j < 4; ++j)
                    acc[i][j] = mfma16(a1f[kkI][i], bv[j], acc[i][j]);
        }
#pragma unroll
        for (int i = 0; i < 4; ++i) {
#pragma unroll
            for (int j = 0; j < 4; ++j) {
                const int pix = j * 16 + lr;
                const int xw = (pix & 7) << 3;
                const int s = wid * 64 + i * 16 + lh * 4;
                const u32 w0 = cvtpk(fmaxf(acc[i][j][0] + bsk[s + 0], 0.f),
                                     fmaxf(acc[i][j][1] + bsk[s + 1], 0.f));
                const u32 w1 = cvtpk(fmaxf(acc[i][j][2] + bsk[s + 2], 0.f),
                                     fmaxf(acc[i][j][3] + bsk[s + 3], 0.f));
                *(u32*)(SK + (pix << 8) + (s ^ xw)) = w0;
                *(u32*)(SK + (pix << 8) + ((s + 2) ^ xw)) = w1;
            }
        }
    }
    __syncthreads();

    // GEMM2 + GEMM3 fused in-register, TWO e-passes, depth-1 W2 pipeline.
    {
        f32x4 acc_out[4];
#pragma unroll
        for (int j = 0; j < 4; ++j) acc_out[j] = (f32x4){0.f, 0.f, 0.f, 0.f};

#pragma unroll
        for (int pass = 0; pass < 2; ++pass) {
            const int ep = wid * 128 + pass * 64;
            const u16* w2b = W2 + (wid * 2 + pass) * 16384 + lane * 8;
            // hoist W3 B-fragments for this pass (in flight through the kkI loop)
            bf16x8 bfr[2];
#pragma unroll
            for (int c = 0; c < 2; ++c)
                bfr[c] = *(const bf16x8*)(W3 + (wid * 2 + pass) * 1024 + c * 512 + lane * 8);
            f32x4 acc[4][4];
#pragma unroll
            for (int i = 0; i < 4; ++i)
#pragma unroll
                for (int j = 0; j < 4; ++j) acc[i][j] = (f32x4){0.f, 0.f, 0.f, 0.f};
            bf16x8 aC[4];
#pragma unroll
            for (int i = 0; i < 4; ++i)
                aC[i] = *(const bf16x8*)(w2b + i * 512);
#pragma unroll
            for (int kkI = 0; kkI < 8; ++kkI) {
                bf16x8 aN[4];
                if (kkI < 7) {
#pragma unroll
                    for (int i = 0; i < 4; ++i)
                        aN[i] = *(const bf16x8*)(w2b + (kkI + 1) * 2048 + i * 512);
                }
                const int kb = kkI * 32 + lh * 8;
                bf16x8 bv[4];
#pragma unroll
                for (int j = 0; j < 4; ++j) {
                    const int pr = j * 16 + lr;
                    bv[j] = *(const bf16x8*)(SK + (pr << 8) + (kb ^ ((pr & 7) << 3)));
                }
#pragma unroll
                for (int i = 0; i < 4; ++i)
#pragma unroll
                    for (int j = 0; j < 4; ++j)
                        acc[i][j] = mfma16(aC[i], bv[j], acc[i][j]);
                if (kkI < 7) {
#pragma unroll
                    for (int i = 0; i < 4; ++i) aC[i] = aN[i];
                }
            }
            // bias + relu + pack (E1 values stay in registers)
            u32 pk[4][4][2];
#pragma unroll
            for (int i = 0; i < 4; ++i) {
#pragma unroll
                for (int j = 0; j < 4; ++j) {
                    const int eb = ep + i * 16 + lh * 4;
                    pk[i][j][0] = cvtpk(fmaxf(acc[i][j][0] + be1[eb + 0], 0.f),
                                        fmaxf(acc[i][j][1] + be1[eb + 1], 0.f));
                    pk[i][j][1] = cvtpk(fmaxf(acc[i][j][2] + be1[eb + 2], 0.f),
                                        fmaxf(acc[i][j][3] + be1[eb + 3], 0.f));
                }
            }
#pragma unroll
            for (int j = 0; j < 4; ++j) {
#pragma unroll
                for (int c = 0; c < 2; ++c) {
                    union { u32 w[4]; bf16x8 v; } af;
                    af.w[0] = pk[2 * c][j][0];
                    af.w[1] = pk[2 * c][j][1];
                    af.w[2] = pk[2 * c + 1][j][0];
                    af.w[3] = pk[2 * c + 1][j][1];
                    acc_out[j] = mfma16(af.v, bfr[c], acc_out[j]);
                }
            }
        }
        __syncthreads();   // all waves done reading SK (both passes); reuse as f32 scratch

        // stage per-wave K-split partials: SKf[wid][pix][p]
        float* SKf = (float*)SK;
#pragma unroll
        for (int j = 0; j < 4; ++j)
#pragma unroll
            for (int r = 0; r < 4; ++r)
                SKf[wid * 1024 + (j * 16 + lh * 4 + r) * 16 + lr] = acc_out[j][r];
    }
    __syncthreads();

    // cross-wave reduce + atomic accumulate into out (pre-initialized with end2_b)
    {
        const f32x4* Sv = (const f32x4*)SK;
        f32x4 sum = Sv[tid] + Sv[256 + tid] + Sv[512 + tid] + Sv[768 + tid];
        const int pix = tid >> 2;
        const int p0 = (tid & 3) << 2;
        if (p0 < 12) {
#pragma unroll
            for (int r = 0; r < 4; ++r)
                atomicAdd(out + (b * 12 + p0 + r) * 512 + n0 + pix, sum[r] * (1.f / 31.f));
        }
    }
}

extern "C" void kernel_launch(void* const* d_in, const int* in_sizes, int n_in,
                              void* d_out, int out_size, void* d_ws, size_t ws_size,
                              hipStream_t stream) {
    const float* x       = (const float*)d_in[0];
    const int*   ei      = (const int*)  d_in[1];
    const float* ew      = (const float*)d_in[2];
    const float* start_w = (const float*)d_in[3];
    const float* start_b = (const float*)d_in[4];
    const float* filt_w  = (const float*)d_in[5];
    const float* filt_b  = (const float*)d_in[6];
    const float* gate_w  = (const float*)d_in[7];
    const float* gate_b  = (const float*)d_in[8];
    const float* gcn_w   = (const float*)d_in[9];
    const float* gcn_b   = (const float*)d_in[10];
    const float* skip_w  = (const float*)d_in[13];
    const float* skip_b  = (const float*)d_in[14];
    const float* end1_w  = (const float*)d_in[15];
    const float* end1_b  = (const float*)d_in[16];
    const float* end2_w  = (const float*)d_in[17];
    const float* end2_b  = (const float*)d_in[18];
    float* out = (float*)d_out;

    char* ws = (char*)d_ws;
    float* S    = (float*)(ws);                 // 1,048,576 B
    float* deg  = (float*)(ws + 1048576);       // 2048 B
    float* rs   = (float*)(ws + 1050624);       // 2048 B   (memset with S+deg)
    float* dis  = (float*)(ws + 1052672);       // 2048 B
    float* coef = (float*)(ws + 1579008);       // 1536 B
    u16*   W1   = (u16*)  (ws + 1580544);       // 32,768 B
    u16*   W2   = (u16*)  (ws + 1613312);       // 262,144 B
    u16*   W3   = (u16*)  (ws + 1875456);       // 16,384 B
    float* Y    = (float*)(ws + 1891840);       // 4 x 524,288 B quarter-partials

    hipMemsetAsync(S, 0, 1048576 + 4096, stream);    // S + deg + rs
    hipLaunchKernelGGL(deg_k,      dim3(34),  dim3(256), 0, stream, ei, ew, deg);
    hipLaunchKernelGGL(dis_coef_k, dim3(195), dim3(256), 0, stream, deg, dis,
                       start_w, start_b, filt_w, filt_b, gate_w, gate_b, gcn_w, coef,
                       end2_b, out);
    hipLaunchKernelGGL(scat_wconv_k, dim3(546), dim3(256), 0, stream, ei, ew, dis,
                       skip_w, end1_w, end2_w, W1, W2, W3, S, rs);
    hipLaunchKernelGGL(y_k,    dim3(8, 64), dim3(256), 0, stream, x, S, Y);
    hipLaunchKernelGGL(fused_k, dim3(1984), dim3(256), 0, stream,
                       x, Y, rs, coef, gcn_b, skip_b, end1_b, W1, W2, W3, out);
}